// Round 1
// baseline (7998.360 us; speedup 1.0000x reference)
//
#include <hip/hip_runtime.h>
#include <math.h>

#define BB 4
#define TT 4
#define CC 256
#define HH 30
#define WW 40
#define HWS (HH*WW)          // 1200
#define CHW (CC*HWS)         // 307200

// ---------------------------------------------------------------------------
// h0 = sum_t x[b,t,:,:,:]; c0 = h0
// ---------------------------------------------------------------------------
__global__ void init_hc(const float* __restrict__ x,
                        float* __restrict__ h, float* __restrict__ c) {
    int id = blockIdx.x * 256 + threadIdx.x;
    if (id >= BB * CHW) return;
    int b = id / CHW;
    int rem = id - b * CHW;
    float s = 0.f;
#pragma unroll
    for (int t = 0; t < TT; ++t)
        s += x[((size_t)b * TT + t) * CHW + rem];
    h[id] = s;
    c[id] = s;
}

// ---------------------------------------------------------------------------
// Dual 3x3 conv: out[b,co,y,:] = act( conv(in1*scale, W1) + conv(in2, W2) + b1 + b2 )
// in1/in2: [B, 256, H, W] with per-source batch stride (xt lives inside x).
// W: HWIO [3,3,256,Cout]. Block: 64 co x 40 pixels (one row). 256 threads.
// ---------------------------------------------------------------------------
__global__ __launch_bounds__(256) void conv_dual(
    const float* __restrict__ in1, long bs1, const float* __restrict__ scale,
    const float* __restrict__ in2, long bs2,
    const float* __restrict__ W1, const float* __restrict__ W2,
    const float* __restrict__ b1, const float* __restrict__ b2,
    float* __restrict__ out, int Cout, int do_tanh)
{
    __shared__ float s_in[8 * 3 * 42];   // [ci][row][x(-1..40)]
    __shared__ float s_w[8 * 9 * 64];    // [ci*9+tap][co]

    const int tid = threadIdx.x;
    const int tx = tid & 63;         // co within tile
    const int ty = tid >> 6;         // pixel group (10 px each)
    const int y = blockIdx.x;
    const int co_base = blockIdx.y * 64;
    const int b = blockIdx.z;
    const int co = co_base + tx;

    const float bias = b1[co] + b2[co];
    float acc[10];
#pragma unroll
    for (int p = 0; p < 10; ++p) acc[p] = bias;

    for (int src = 0; src < 2; ++src) {
        const float* inp = src ? in2 : in1;
        const long bs = src ? bs2 : bs1;
        const float* wgt = src ? W2 : W1;
        const float* scl = src ? nullptr : scale;

        for (int ci0 = 0; ci0 < CC; ci0 += 8) {
            __syncthreads();
            // stage input chunk: 8 ci x 3 rows x 42 (zero-padded)
            for (int i = tid; i < 8 * 3 * 42; i += 256) {
                int ci = i / 126;
                int rem = i - ci * 126;
                int r = rem / 42;
                int xx = rem - r * 42 - 1;
                int yy = y + r - 1;
                float v = 0.f;
                if (xx >= 0 && xx < WW && yy >= 0 && yy < HH) {
                    v = inp[(size_t)b * bs + ((size_t)(ci0 + ci) * HH + yy) * WW + xx];
                    if (scl) v *= scl[(size_t)b * HWS + yy * WW + xx];
                }
                s_in[i] = v;
            }
            // stage weights: 8 ci x 9 taps x 64 co (coalesced over co)
            for (int i = tid; i < 8 * 9 * 64; i += 256) {
                int co_l = i & 63;
                int rest = i >> 6;          // ci*9 + tap
                int ci = rest / 9;
                int tap = rest - ci * 9;
                s_w[i] = wgt[((size_t)tap * CC + ci0 + ci) * Cout + co_base + co_l];
            }
            __syncthreads();

#pragma unroll
            for (int ci = 0; ci < 8; ++ci) {
#pragma unroll
                for (int dy = 0; dy < 3; ++dy) {
                    float w0 = s_w[(ci * 9 + dy * 3 + 0) * 64 + tx];
                    float w1 = s_w[(ci * 9 + dy * 3 + 1) * 64 + tx];
                    float w2 = s_w[(ci * 9 + dy * 3 + 2) * 64 + tx];
                    const float* row = &s_in[(ci * 3 + dy) * 42 + ty * 10];
#pragma unroll
                    for (int p = 0; p < 10; ++p)
                        acc[p] = fmaf(w0, row[p],
                                 fmaf(w1, row[p + 1],
                                 fmaf(w2, row[p + 2], acc[p])));
                }
            }
        }
    }

    size_t obase = (((size_t)b * Cout + co) * HH + y) * WW + ty * 10;
#pragma unroll
    for (int p = 0; p < 10; ++p) {
        float v = acc[p];
        if (do_tanh) v = tanhf(v);
        out[obase + p] = v;
    }
}

// ---------------------------------------------------------------------------
// e[b,y,x] = sum_{ca,tap} att[b,ca,y+dy-1,x+dx-1] * Va[tap,ca]
// ---------------------------------------------------------------------------
__global__ void att_e_kernel(const float* __restrict__ att,
                             const float* __restrict__ Va,
                             float* __restrict__ e) {
    int id = blockIdx.x * 256 + threadIdx.x;
    if (id >= BB * HWS) return;
    int b = id / HWS;
    int rem = id - b * HWS;
    int y = rem / WW;
    int x = rem - y * WW;
    float acc = 0.f;
    for (int ca = 0; ca < CC; ++ca) {
        const float* base = att + ((size_t)b * CC + ca) * HWS;
#pragma unroll
        for (int dy = 0; dy < 3; ++dy) {
            int yy = y + dy - 1;
            if (yy < 0 || yy >= HH) continue;
#pragma unroll
            for (int dx = 0; dx < 3; ++dx) {
                int xx = x + dx - 1;
                if (xx < 0 || xx >= WW) continue;
                acc = fmaf(base[yy * WW + xx], Va[(dy * 3 + dx) * CC + ca], acc);
            }
        }
    }
    e[id] = acc;
}

// ---------------------------------------------------------------------------
// softmax over HW per batch
// ---------------------------------------------------------------------------
__global__ void softmax_kernel(const float* __restrict__ e, float* __restrict__ a) {
    __shared__ float red[256];
    int b = blockIdx.x;
    int tid = threadIdx.x;
    const float* eb = e + (size_t)b * HWS;

    float m = -1e30f;
    for (int i = tid; i < HWS; i += 256) m = fmaxf(m, eb[i]);
    red[tid] = m;
    __syncthreads();
    for (int s = 128; s > 0; s >>= 1) {
        if (tid < s) red[tid] = fmaxf(red[tid], red[tid + s]);
        __syncthreads();
    }
    m = red[0];
    __syncthreads();

    float sum = 0.f;
    for (int i = tid; i < HWS; i += 256) sum += expf(eb[i] - m);
    red[tid] = sum;
    __syncthreads();
    for (int s = 128; s > 0; s >>= 1) {
        if (tid < s) red[tid] += red[tid + s];
        __syncthreads();
    }
    float inv = 1.f / red[0];
    for (int i = tid; i < HWS; i += 256)
        a[(size_t)b * HWS + i] = expf(eb[i] - m) * inv;
}

// ---------------------------------------------------------------------------
// LSTM gate update: g=[b,4C,H,W] order i|f|c|o ; c in/out, h_out written
// ---------------------------------------------------------------------------
__global__ void gate_update(const float* __restrict__ g, float* __restrict__ c,
                            float* __restrict__ h_out) {
    int id = blockIdx.x * 256 + threadIdx.x;
    if (id >= BB * CHW) return;
    int b = id / CHW;
    int rem = id - b * CHW;    // c*HW + p
    size_t gbase = (size_t)b * 4 * CHW + rem;
    float gi = g[gbase];
    float gf = g[gbase + CHW];
    float gc = g[gbase + 2 * (size_t)CHW];
    float go = g[gbase + 3 * (size_t)CHW];
    float i_ = 1.f / (1.f + expf(-gi));
    float f_ = 1.f / (1.f + expf(-gf));
    float o_ = 1.f / (1.f + expf(-go));
    float cn = f_ * c[id] + i_ * tanhf(gc);
    c[id] = cn;
    h_out[id] = o_ * tanhf(cn);
}

// ---------------------------------------------------------------------------
extern "C" void kernel_launch(void* const* d_in, const int* in_sizes, int n_in,
                              void* d_out, int out_size, void* d_ws, size_t ws_size,
                              hipStream_t stream) {
    const float* x   = (const float*)d_in[0];
    const float* Wa  = (const float*)d_in[1];
    const float* ba  = (const float*)d_in[2];
    const float* Ua  = (const float*)d_in[3];
    const float* bua = (const float*)d_in[4];
    const float* Va  = (const float*)d_in[5];
    const float* Wx  = (const float*)d_in[6];
    const float* bx  = (const float*)d_in[7];
    const float* Uh  = (const float*)d_in[8];
    const float* bh  = (const float*)d_in[9];
    float* out = (float*)d_out;

    float* ws = (float*)d_ws;
    const size_t NCHW = (size_t)BB * CHW;           // 1,228,800
    float* h0  = ws;
    float* h1  = h0  + NCHW;
    float* cb  = h1  + NCHW;
    float* att = cb  + NCHW;
    float* g   = att + NCHW;                        // 4*NCHW
    float* e   = g   + 4 * NCHW;
    float* a   = e   + (size_t)BB * HWS;

    const int n = (int)NCHW;
    init_hc<<<dim3((n + 255) / 256), dim3(256), 0, stream>>>(x, h0, cb);

    float* hbuf[2] = {h0, h1};
    const long XT_BS = (long)TT * CHW;   // batch stride inside x for a fixed t
    const long H_BS  = (long)CHW;

    for (int t = 0; t < TT; ++t) {
        const float* xt = x + (size_t)t * CHW;
        float* hcur = hbuf[t & 1];
        float* hnext = (t == TT - 1) ? out : hbuf[(t + 1) & 1];

        // attention: att = tanh(conv(h,Wa,ba) + conv(xt,Ua,bua))
        conv_dual<<<dim3(HH, CC / 64, BB), dim3(256), 0, stream>>>(
            hcur, H_BS, nullptr, xt, XT_BS, Wa, Ua, ba, bua, att, CC, 1);

        // e = conv(att, Va)
        att_e_kernel<<<dim3((BB * HWS + 255) / 256), dim3(256), 0, stream>>>(att, Va, e);

        // a = softmax(e) per batch
        softmax_kernel<<<dim3(BB), dim3(256), 0, stream>>>(e, a);

        // gates: g = conv(xt*a, Wx, bx) + conv(h, Uh, bh)
        conv_dual<<<dim3(HH, (4 * CC) / 64, BB), dim3(256), 0, stream>>>(
            xt, XT_BS, a, hcur, H_BS, Wx, Uh, bx, bh, g, 4 * CC, 0);

        // pointwise LSTM update
        gate_update<<<dim3((n + 255) / 256), dim3(256), 0, stream>>>(g, cb, hnext);
    }
}

// Round 2
// 2063.148 us; speedup vs baseline: 3.8768x; 3.8768x over previous
//
#include <hip/hip_runtime.h>
#include <math.h>

#define BB 4
#define TT 4
#define CC 256
#define HH 30
#define WW 40
#define HWS (HH*WW)          // 1200
#define CHW (CC*HWS)         // 307200

typedef __attribute__((ext_vector_type(8))) short short8;
typedef __attribute__((ext_vector_type(4))) float f32x4;

__device__ __forceinline__ unsigned short f2bf(float f) {
    unsigned u = __float_as_uint(f);
    unsigned r = (u + 0x7fffu + ((u >> 16) & 1u)) >> 16;
    return (unsigned short)r;
}
__device__ __forceinline__ float bf2f(unsigned short h) {
    return __uint_as_float(((unsigned)h) << 16);
}

// ---------------------------------------------------------------------------
// h0 = sum_t x[b,t,:,:,:]; c0 = h0
// ---------------------------------------------------------------------------
__global__ void init_hc(const float* __restrict__ x,
                        float* __restrict__ h, float* __restrict__ c) {
    int id = blockIdx.x * 256 + threadIdx.x;
    if (id >= BB * CHW) return;
    int b = id / CHW;
    int rem = id - b * CHW;
    float s = 0.f;
#pragma unroll
    for (int t = 0; t < TT; ++t)
        s += x[((size_t)b * TT + t) * CHW + rem];
    h[id] = s;
    c[id] = s;
}

// ---------------------------------------------------------------------------
// Pre-split weights into packed bf16 hi/lo: layout [kg=k/8][Cout][k%8]
// k = (src? 2304:0) + tap*256 + ci  over K=4608 (W1 = src0 weights, W2 = src1)
// ---------------------------------------------------------------------------
__global__ void pack_weights(const float* __restrict__ W1,
                             const float* __restrict__ W2,
                             short* __restrict__ hi, short* __restrict__ lo,
                             int Cout) {
    int idx = blockIdx.x * 256 + threadIdx.x;
    if (idx >= 4608 * Cout) return;
    int k = idx / Cout;
    int n = idx - k * Cout;
    float v = (k < 2304) ? W1[(size_t)k * Cout + n]
                         : W2[(size_t)(k - 2304) * Cout + n];
    unsigned short h = f2bf(v);
    unsigned short l = f2bf(v - bf2f(h));
    size_t o = ((size_t)(k >> 3) * Cout + n) * 8 + (k & 7);
    hi[o] = (short)h;
    lo[o] = (short)l;
}

// ---------------------------------------------------------------------------
// MFMA dual 3x3 conv, split-bf16 (3 MFMAs per logical fp32 MAC group):
//   out = act( conv(in0*scale, W1) + conv(in1, W2) + b1 + b2 )
// M-tile: 80 pixels (2 rows of one (b,y) pair), 5 MFMA m-tiles.
// N-tile: 4 waves * NW*16.  A staged in LDS [pix(4x42 halo)][ci pad 40] bf16
// hi/lo; B read directly from packed global wt (coalesced 16B/lane).
// ---------------------------------------------------------------------------
template<int NW, bool DO_TANH>
__global__ __launch_bounds__(256) void conv_mfma(
    const float* __restrict__ in0, long bs0, const float* __restrict__ scale,
    const float* __restrict__ in1, long bs1,
    const short* __restrict__ wt_hi, const short* __restrict__ wt_lo,
    const float* __restrict__ b1, const float* __restrict__ b2,
    float* __restrict__ out, int Cout)
{
    __shared__ short s_ah[168 * 40];
    __shared__ short s_al[168 * 40];

    const int tid = threadIdx.x;
    const int l = tid & 63, wv = tid >> 6;
    const int q = l >> 4, r = l & 15;
    const int mb = blockIdx.x;                 // 0..59
    const int b = mb / 15;
    const int pix0 = (mb % 15) * 80;           // within-batch pixel base
    const int y0 = (mb % 15) * 2;
    const int n0 = blockIdx.y * (4 * NW * 16) + wv * (NW * 16);

    f32x4 acc[5][NW];
#pragma unroll
    for (int nt = 0; nt < NW; ++nt) {
        int co = n0 + nt * 16 + r;
        float bias = b1[co] + b2[co];
        f32x4 bv = {bias, bias, bias, bias};
#pragma unroll
        for (int mt = 0; mt < 5; ++mt) acc[mt][nt] = bv;
    }

    for (int src = 0; src < 2; ++src) {
        const float* inp = (src ? in1 + (size_t)b * bs1 : in0 + (size_t)b * bs0);
        const float* scl = (src == 0) ? scale : nullptr;
        for (int ci0 = 0; ci0 < CC; ci0 += 32) {
            __syncthreads();
            for (int i = tid; i < 32 * 168; i += 256) {
                int ci = i / 168;
                int pix = i - ci * 168;
                int row = pix / 42;
                int px = pix - row * 42;
                int xx = px - 1, yy = y0 + row - 1;
                float v = 0.f;
                if (xx >= 0 && xx < WW && yy >= 0 && yy < HH) {
                    v = inp[(size_t)(ci0 + ci) * HWS + yy * WW + xx];
                    if (scl) v *= scl[(size_t)b * HWS + yy * WW + xx];
                }
                unsigned short h = f2bf(v);
                unsigned short lo = f2bf(v - bf2f(h));
                s_ah[pix * 40 + ci] = (short)h;
                s_al[pix * 40 + ci] = (short)lo;
            }
            __syncthreads();

            const int kgb = src * 288 + (ci0 >> 3);
#pragma unroll
            for (int tap = 0; tap < 9; ++tap) {
                const int dy = tap / 3, dx = tap - dy * 3;
                const int kg = kgb + tap * 32 + q;
                short8 bh[NW], bl[NW];
#pragma unroll
                for (int nt = 0; nt < NW; ++nt) {
                    size_t off = (size_t)kg * Cout + (n0 + nt * 16 + r);
                    bh[nt] = ((const short8*)wt_hi)[off];
                    bl[nt] = ((const short8*)wt_lo)[off];
                }
#pragma unroll
                for (int mt = 0; mt < 5; ++mt) {
                    int p = mt * 16 + r;               // pixel within 80
                    int ry = p / 40, rx = p - ry * 40;
                    int pix = (ry + dy) * 42 + rx + dx;
                    short8 ah = *(const short8*)&s_ah[pix * 40 + q * 8];
                    short8 al = *(const short8*)&s_al[pix * 40 + q * 8];
#pragma unroll
                    for (int nt = 0; nt < NW; ++nt) {
                        acc[mt][nt] = __builtin_amdgcn_mfma_f32_16x16x32_bf16(
                            ah, bh[nt], acc[mt][nt], 0, 0, 0);
                        acc[mt][nt] = __builtin_amdgcn_mfma_f32_16x16x32_bf16(
                            al, bh[nt], acc[mt][nt], 0, 0, 0);
                        acc[mt][nt] = __builtin_amdgcn_mfma_f32_16x16x32_bf16(
                            ah, bl[nt], acc[mt][nt], 0, 0, 0);
                    }
                }
            }
        }
    }

    // epilogue: D row(m) = q*4+reg, col(n) = r
#pragma unroll
    for (int mt = 0; mt < 5; ++mt) {
#pragma unroll
        for (int nt = 0; nt < NW; ++nt) {
            int co = n0 + nt * 16 + r;
            int p = pix0 + mt * 16 + q * 4;
            f32x4 v = acc[mt][nt];
            if (DO_TANH) {
                v.x = tanhf(v.x); v.y = tanhf(v.y);
                v.z = tanhf(v.z); v.w = tanhf(v.w);
            }
            *(f32x4*)&out[((size_t)b * Cout + co) * HWS + p] = v;
        }
    }
}

// ---------------------------------------------------------------------------
// e[b,y,x] = sum_{ca,tap} att[b,ca,y+dy-1,x+dx-1] * Va[tap,ca]
// one block per (b,y) row; 6 ca-groups x 40 x
// ---------------------------------------------------------------------------
__global__ void att_e_row(const float* __restrict__ att,
                          const float* __restrict__ Va,
                          float* __restrict__ e) {
    __shared__ float red[6][40];
    int blk = blockIdx.x;
    int b = blk / HH, y = blk - b * HH;
    int t = threadIdx.x;
    if (t < 240) {
        int x = t % 40, g = t / 40;
        float acc = 0.f;
        for (int ca = g; ca < CC; ca += 6) {
            const float* base = att + ((size_t)b * CC + ca) * HWS;
#pragma unroll
            for (int dy = 0; dy < 3; ++dy) {
                int yy = y + dy - 1;
                if (yy < 0 || yy >= HH) continue;
#pragma unroll
                for (int dx = 0; dx < 3; ++dx) {
                    int xx = x + dx - 1;
                    if (xx < 0 || xx >= WW) continue;
                    acc = fmaf(base[yy * WW + xx], Va[(dy * 3 + dx) * CC + ca], acc);
                }
            }
        }
        red[g][x] = acc;
    }
    __syncthreads();
    if (t < 40) {
        float s = red[0][t] + red[1][t] + red[2][t] + red[3][t] + red[4][t] + red[5][t];
        e[(size_t)(b * HH + y) * WW + t] = s;
    }
}

// ---------------------------------------------------------------------------
// softmax over HW per batch
// ---------------------------------------------------------------------------
__global__ void softmax_kernel(const float* __restrict__ e, float* __restrict__ a) {
    __shared__ float red[256];
    int b = blockIdx.x;
    int tid = threadIdx.x;
    const float* eb = e + (size_t)b * HWS;

    float m = -1e30f;
    for (int i = tid; i < HWS; i += 256) m = fmaxf(m, eb[i]);
    red[tid] = m;
    __syncthreads();
    for (int s = 128; s > 0; s >>= 1) {
        if (tid < s) red[tid] = fmaxf(red[tid], red[tid + s]);
        __syncthreads();
    }
    m = red[0];
    __syncthreads();

    float sum = 0.f;
    for (int i = tid; i < HWS; i += 256) sum += expf(eb[i] - m);
    red[tid] = sum;
    __syncthreads();
    for (int s = 128; s > 0; s >>= 1) {
        if (tid < s) red[tid] += red[tid + s];
        __syncthreads();
    }
    float inv = 1.f / red[0];
    for (int i = tid; i < HWS; i += 256)
        a[(size_t)b * HWS + i] = expf(eb[i] - m) * inv;
}

// ---------------------------------------------------------------------------
// LSTM gate update: g=[b,4C,H,W] order i|f|c|o ; c in/out, h_out written
// ---------------------------------------------------------------------------
__global__ void gate_update(const float* __restrict__ g, float* __restrict__ c,
                            float* __restrict__ h_out) {
    int id = blockIdx.x * 256 + threadIdx.x;
    if (id >= BB * CHW) return;
    int b = id / CHW;
    int rem = id - b * CHW;
    size_t gbase = (size_t)b * 4 * CHW + rem;
    float gi = g[gbase];
    float gf = g[gbase + CHW];
    float gc = g[gbase + 2 * (size_t)CHW];
    float go = g[gbase + 3 * (size_t)CHW];
    float i_ = 1.f / (1.f + expf(-gi));
    float f_ = 1.f / (1.f + expf(-gf));
    float o_ = 1.f / (1.f + expf(-go));
    float cn = f_ * c[id] + i_ * tanhf(gc);
    c[id] = cn;
    h_out[id] = o_ * tanhf(cn);
}

// ---------------------------------------------------------------------------
extern "C" void kernel_launch(void* const* d_in, const int* in_sizes, int n_in,
                              void* d_out, int out_size, void* d_ws, size_t ws_size,
                              hipStream_t stream) {
    const float* x   = (const float*)d_in[0];
    const float* Wa  = (const float*)d_in[1];
    const float* ba  = (const float*)d_in[2];
    const float* Ua  = (const float*)d_in[3];
    const float* bua = (const float*)d_in[4];
    const float* Va  = (const float*)d_in[5];
    const float* Wx  = (const float*)d_in[6];
    const float* bx  = (const float*)d_in[7];
    const float* Uh  = (const float*)d_in[8];
    const float* bh  = (const float*)d_in[9];
    float* out = (float*)d_out;

    char* wsb = (char*)d_ws;
    const size_t NCHW = (size_t)BB * CHW;
    // packed weights (bf16 shorts)
    short* wtg_hi = (short*)wsb;                  wsb += (size_t)4608 * 1024 * 2;
    short* wtg_lo = (short*)wsb;                  wsb += (size_t)4608 * 1024 * 2;
    short* wta_hi = (short*)wsb;                  wsb += (size_t)4608 * 256 * 2;
    short* wta_lo = (short*)wsb;                  wsb += (size_t)4608 * 256 * 2;
    float* h0  = (float*)wsb;                     wsb += NCHW * 4;
    float* h1  = (float*)wsb;                     wsb += NCHW * 4;
    float* cb  = (float*)wsb;                     wsb += NCHW * 4;
    float* att = (float*)wsb;                     wsb += NCHW * 4;
    float* g   = (float*)wsb;                     wsb += 4 * NCHW * 4;
    float* e   = (float*)wsb;                     wsb += (size_t)BB * HWS * 4;
    float* a   = (float*)wsb;

    // prep: pack/split weights (once per launch; weights constant over t)
    pack_weights<<<dim3((4608 * 1024 + 255) / 256), dim3(256), 0, stream>>>(
        Wx, Uh, wtg_hi, wtg_lo, 1024);
    pack_weights<<<dim3((4608 * 256 + 255) / 256), dim3(256), 0, stream>>>(
        Wa, Ua, wta_hi, wta_lo, 256);

    const int n = (int)NCHW;
    init_hc<<<dim3((n + 255) / 256), dim3(256), 0, stream>>>(x, h0, cb);

    float* hbuf[2] = {h0, h1};
    const long XT_BS = (long)TT * CHW;
    const long H_BS  = (long)CHW;

    for (int t = 0; t < TT; ++t) {
        const float* xt = x + (size_t)t * CHW;
        float* hcur = hbuf[t & 1];
        float* hnext = (t == TT - 1) ? out : hbuf[(t + 1) & 1];

        // attention: att = tanh(conv(h,Wa,ba) + conv(xt,Ua,bua))   [src0=h]
        conv_mfma<1, true><<<dim3(60, 256 / 64), dim3(256), 0, stream>>>(
            hcur, H_BS, nullptr, xt, XT_BS, wta_hi, wta_lo, ba, bua, att, 256);

        // e = conv(att, Va); a = softmax(e)
        att_e_row<<<dim3(BB * HH), dim3(256), 0, stream>>>(att, Va, e);
        softmax_kernel<<<dim3(BB), dim3(256), 0, stream>>>(e, a);

        // gates: g = conv(xt*a, Wx, bx) + conv(h, Uh, bh)          [src0=xt]
        conv_mfma<2, false><<<dim3(60, 1024 / 128), dim3(256), 0, stream>>>(
            xt, XT_BS, a, hcur, H_BS, wtg_hi, wtg_lo, bx, bh, g, 1024);

        gate_update<<<dim3((n + 255) / 256), dim3(256), 0, stream>>>(g, cb, hnext);
    }
}

// Round 3
// 1215.605 us; speedup vs baseline: 6.5797x; 1.6972x over previous
//
#include <hip/hip_runtime.h>
#include <math.h>

#define BB 4
#define TT 4
#define CC 256
#define HH 30
#define WW 40
#define HWS (HH*WW)          // 1200
#define CHW (CC*HWS)         // 307200

typedef __attribute__((ext_vector_type(8))) short short8;
typedef __attribute__((ext_vector_type(4))) float f32x4;

__device__ __forceinline__ unsigned short f2bf(float f) {
    unsigned u = __float_as_uint(f);
    unsigned r = (u + 0x7fffu + ((u >> 16) & 1u)) >> 16;
    return (unsigned short)r;
}
__device__ __forceinline__ float bf2f(unsigned short h) {
    return __uint_as_float(((unsigned)h) << 16);
}

// ---------------------------------------------------------------------------
// h0 = sum_t x[b,t,:,:,:]; c0 = h0
// ---------------------------------------------------------------------------
__global__ void init_hc(const float* __restrict__ x,
                        float* __restrict__ h, float* __restrict__ c) {
    int id = blockIdx.x * 256 + threadIdx.x;
    if (id >= BB * CHW) return;
    int b = id / CHW;
    int rem = id - b * CHW;
    float s = 0.f;
#pragma unroll
    for (int t = 0; t < TT; ++t)
        s += x[((size_t)b * TT + t) * CHW + rem];
    h[id] = s;
    c[id] = s;
}

// ---------------------------------------------------------------------------
// Pre-split weights into packed bf16 hi/lo: layout [kg=k/8][Cout][k%8]
// k = (src? 2304:0) + tap*256 + ci  over K=4608
// ---------------------------------------------------------------------------
__global__ void pack_weights(const float* __restrict__ W1,
                             const float* __restrict__ W2,
                             short* __restrict__ hi, short* __restrict__ lo,
                             int Cout) {
    int idx = blockIdx.x * 256 + threadIdx.x;
    if (idx >= 4608 * Cout) return;
    int k = idx / Cout;
    int n = idx - k * Cout;
    float v = (k < 2304) ? W1[(size_t)k * Cout + n]
                         : W2[(size_t)(k - 2304) * Cout + n];
    unsigned short h = f2bf(v);
    unsigned short l = f2bf(v - bf2f(h));
    size_t o = ((size_t)(k >> 3) * Cout + n) * 8 + (k & 7);
    hi[o] = (short)h;
    lo[o] = (short)l;
}

// ---------------------------------------------------------------------------
// MFMA dual 3x3 conv, split-bf16, K-split over the two sources (blockIdx.z):
//   z=0: partial = conv(in0*scale, W1) + b1 + b2   (bias folded here)
//   z=1: partial = conv(in1, W2)
// out has two stacked [B,Cout,H,W] buffers (z selects).
// M-tile: 80 pixels (2 rows). LDS layout [cig(4)][pix(168)][8ci] bf16 hi/lo:
// 16B-granular => conflict-free staging writes and frag reads.
// B (weights) read directly from packed global (256B/quad, L2-served).
// ---------------------------------------------------------------------------
template<int NW>
__global__ __launch_bounds__(256) void conv_mfma(
    const float* __restrict__ in0, long bs0, const float* __restrict__ scale,
    const float* __restrict__ in1, long bs1,
    const short* __restrict__ wt_hi, const short* __restrict__ wt_lo,
    const float* __restrict__ b1, const float* __restrict__ b2,
    float* __restrict__ out, int Cout)
{
    __shared__ alignas(16) short s_ah[4 * 168 * 8];
    __shared__ alignas(16) short s_al[4 * 168 * 8];

    const int tid = threadIdx.x;
    const int l = tid & 63, wv = tid >> 6;
    const int q = l >> 4, r = l & 15;
    const int mb = blockIdx.x;                 // 0..59
    const int b = mb / 15;
    const int pix0 = (mb % 15) * 80;
    const int y0 = (mb % 15) * 2;
    const int n0 = blockIdx.y * (4 * NW * 16) + wv * (NW * 16);
    const int z = blockIdx.z;

    const float* inp = z ? (in1 + (size_t)b * bs1) : (in0 + (size_t)b * bs0);
    const float* scl = z ? nullptr : scale;

    f32x4 acc[5][NW];
#pragma unroll
    for (int nt = 0; nt < NW; ++nt) {
        int co = n0 + nt * 16 + r;
        float bias = z ? 0.f : (b1[co] + b2[co]);
        f32x4 bv = {bias, bias, bias, bias};
#pragma unroll
        for (int mt = 0; mt < 5; ++mt) acc[mt][nt] = bv;
    }

    for (int ci0 = 0; ci0 < CC; ci0 += 32) {
        __syncthreads();
        // stage 32 ci x 168 halo pixels, 8 ci per item, b128 writes
        for (int i = tid; i < 672; i += 256) {
            int cig = i / 168;
            int pix = i - cig * 168;
            int row = pix / 42;
            int px = pix - row * 42;
            int xx = px - 1, yy = y0 + row - 1;
            short8 hv = {0,0,0,0,0,0,0,0};
            short8 lv = {0,0,0,0,0,0,0,0};
            if (xx >= 0 && xx < WW && yy >= 0 && yy < HH) {
                const float* p0 = inp + (size_t)(ci0 + cig * 8) * HWS + yy * WW + xx;
                float sc = scl ? scl[(size_t)b * HWS + yy * WW + xx] : 1.f;
#pragma unroll
                for (int j = 0; j < 8; ++j) {
                    float v = p0[(size_t)j * HWS] * sc;
                    unsigned short h = f2bf(v);
                    hv[j] = (short)h;
                    lv[j] = (short)f2bf(v - bf2f(h));
                }
            }
            *(short8*)&s_ah[(cig * 168 + pix) * 8] = hv;
            *(short8*)&s_al[(cig * 168 + pix) * 8] = lv;
        }
        __syncthreads();

        const int kgb = z * 288 + (ci0 >> 3);
#pragma unroll
        for (int tap = 0; tap < 9; ++tap) {
            const int dy = tap / 3, dx = tap - dy * 3;
            const int kg = kgb + tap * 32 + q;
            short8 bh[NW], bl[NW];
#pragma unroll
            for (int nt = 0; nt < NW; ++nt) {
                size_t off = (size_t)kg * Cout + (n0 + nt * 16 + r);
                bh[nt] = ((const short8*)wt_hi)[off];
                bl[nt] = ((const short8*)wt_lo)[off];
            }
#pragma unroll
            for (int mt = 0; mt < 5; ++mt) {
                int p = mt * 16 + r;
                int ry = p / 40, rx = p - ry * 40;
                int hpix = (ry + dy) * 42 + rx + dx;
                short8 ah = *(const short8*)&s_ah[(q * 168 + hpix) * 8];
                short8 al = *(const short8*)&s_al[(q * 168 + hpix) * 8];
#pragma unroll
                for (int nt = 0; nt < NW; ++nt) {
                    acc[mt][nt] = __builtin_amdgcn_mfma_f32_16x16x32_bf16(
                        ah, bh[nt], acc[mt][nt], 0, 0, 0);
                    acc[mt][nt] = __builtin_amdgcn_mfma_f32_16x16x32_bf16(
                        al, bh[nt], acc[mt][nt], 0, 0, 0);
                    acc[mt][nt] = __builtin_amdgcn_mfma_f32_16x16x32_bf16(
                        ah, bl[nt], acc[mt][nt], 0, 0, 0);
                }
            }
        }
    }

    out += (size_t)z * BB * Cout * HWS;
#pragma unroll
    for (int mt = 0; mt < 5; ++mt) {
#pragma unroll
        for (int nt = 0; nt < NW; ++nt) {
            int co = n0 + nt * 16 + r;
            int p = pix0 + mt * 16 + q * 4;
            *(f32x4*)&out[((size_t)b * Cout + co) * HWS + p] = acc[mt][nt];
        }
    }
}

// ---------------------------------------------------------------------------
// att = tanh(a0 + a1)
// ---------------------------------------------------------------------------
__global__ void add_tanh(const float* __restrict__ a0, const float* __restrict__ a1,
                         float* __restrict__ o, int n) {
    int id = blockIdx.x * 256 + threadIdx.x;
    if (id < n) o[id] = tanhf(a0[id] + a1[id]);
}

// ---------------------------------------------------------------------------
// e[b,y,x] = sum_{ca,tap} att[b,ca,y+dy-1,x+dx-1] * Va[tap,ca]
// ---------------------------------------------------------------------------
__global__ void att_e_row(const float* __restrict__ att,
                          const float* __restrict__ Va,
                          float* __restrict__ e) {
    __shared__ float red[6][40];
    int blk = blockIdx.x;
    int b = blk / HH, y = blk - b * HH;
    int t = threadIdx.x;
    if (t < 240) {
        int x = t % 40, g = t / 40;
        float acc = 0.f;
        for (int ca = g; ca < CC; ca += 6) {
            const float* base = att + ((size_t)b * CC + ca) * HWS;
#pragma unroll
            for (int dy = 0; dy < 3; ++dy) {
                int yy = y + dy - 1;
                if (yy < 0 || yy >= HH) continue;
#pragma unroll
                for (int dx = 0; dx < 3; ++dx) {
                    int xx = x + dx - 1;
                    if (xx < 0 || xx >= WW) continue;
                    acc = fmaf(base[yy * WW + xx], Va[(dy * 3 + dx) * CC + ca], acc);
                }
            }
        }
        red[g][x] = acc;
    }
    __syncthreads();
    if (t < 40) {
        float s = red[0][t] + red[1][t] + red[2][t] + red[3][t] + red[4][t] + red[5][t];
        e[(size_t)(b * HH + y) * WW + t] = s;
    }
}

// ---------------------------------------------------------------------------
// softmax over HW per batch
// ---------------------------------------------------------------------------
__global__ void softmax_kernel(const float* __restrict__ e, float* __restrict__ a) {
    __shared__ float red[256];
    int b = blockIdx.x;
    int tid = threadIdx.x;
    const float* eb = e + (size_t)b * HWS;

    float m = -1e30f;
    for (int i = tid; i < HWS; i += 256) m = fmaxf(m, eb[i]);
    red[tid] = m;
    __syncthreads();
    for (int s = 128; s > 0; s >>= 1) {
        if (tid < s) red[tid] = fmaxf(red[tid], red[tid + s]);
        __syncthreads();
    }
    m = red[0];
    __syncthreads();

    float sum = 0.f;
    for (int i = tid; i < HWS; i += 256) sum += expf(eb[i] - m);
    red[tid] = sum;
    __syncthreads();
    for (int s = 128; s > 0; s >>= 1) {
        if (tid < s) red[tid] += red[tid + s];
        __syncthreads();
    }
    float inv = 1.f / red[0];
    for (int i = tid; i < HWS; i += 256)
        a[(size_t)b * HWS + i] = expf(eb[i] - m) * inv;
}

// ---------------------------------------------------------------------------
// LSTM gate update, fusing the K-split partial sum: g = g0 + g1
// ---------------------------------------------------------------------------
__global__ void gate_update(const float* __restrict__ g0, const float* __restrict__ g1,
                            float* __restrict__ c, float* __restrict__ h_out) {
    int id = blockIdx.x * 256 + threadIdx.x;
    if (id >= BB * CHW) return;
    int b = id / CHW;
    int rem = id - b * CHW;
    size_t gbase = (size_t)b * 4 * CHW + rem;
    float gi = g0[gbase] + g1[gbase];
    float gf = g0[gbase + CHW] + g1[gbase + CHW];
    float gc = g0[gbase + 2 * (size_t)CHW] + g1[gbase + 2 * (size_t)CHW];
    float go = g0[gbase + 3 * (size_t)CHW] + g1[gbase + 3 * (size_t)CHW];
    float i_ = 1.f / (1.f + expf(-gi));
    float f_ = 1.f / (1.f + expf(-gf));
    float o_ = 1.f / (1.f + expf(-go));
    float cn = f_ * c[id] + i_ * tanhf(gc);
    c[id] = cn;
    h_out[id] = o_ * tanhf(cn);
}

// ---------------------------------------------------------------------------
extern "C" void kernel_launch(void* const* d_in, const int* in_sizes, int n_in,
                              void* d_out, int out_size, void* d_ws, size_t ws_size,
                              hipStream_t stream) {
    const float* x   = (const float*)d_in[0];
    const float* Wa  = (const float*)d_in[1];
    const float* ba  = (const float*)d_in[2];
    const float* Ua  = (const float*)d_in[3];
    const float* bua = (const float*)d_in[4];
    const float* Va  = (const float*)d_in[5];
    const float* Wx  = (const float*)d_in[6];
    const float* bx  = (const float*)d_in[7];
    const float* Uh  = (const float*)d_in[8];
    const float* bh  = (const float*)d_in[9];
    float* out = (float*)d_out;

    char* wsb = (char*)d_ws;
    const size_t NCHW = (size_t)BB * CHW;
    short* wtg_hi = (short*)wsb;                  wsb += (size_t)4608 * 1024 * 2;
    short* wtg_lo = (short*)wsb;                  wsb += (size_t)4608 * 1024 * 2;
    short* wta_hi = (short*)wsb;                  wsb += (size_t)4608 * 256 * 2;
    short* wta_lo = (short*)wsb;                  wsb += (size_t)4608 * 256 * 2;
    float* h0   = (float*)wsb;                    wsb += NCHW * 4;
    float* h1   = (float*)wsb;                    wsb += NCHW * 4;
    float* cb   = (float*)wsb;                    wsb += NCHW * 4;
    float* att01= (float*)wsb;                    wsb += 2 * NCHW * 4;   // z-stacked
    float* att  = (float*)wsb;                    wsb += NCHW * 4;
    float* g01  = (float*)wsb;                    wsb += 8 * NCHW * 4;   // z-stacked
    float* e    = (float*)wsb;                    wsb += (size_t)BB * HWS * 4;
    float* a    = (float*)wsb;

    pack_weights<<<dim3((4608 * 1024 + 255) / 256), dim3(256), 0, stream>>>(
        Wx, Uh, wtg_hi, wtg_lo, 1024);
    pack_weights<<<dim3((4608 * 256 + 255) / 256), dim3(256), 0, stream>>>(
        Wa, Ua, wta_hi, wta_lo, 256);

    const int n = (int)NCHW;
    init_hc<<<dim3((n + 255) / 256), dim3(256), 0, stream>>>(x, h0, cb);

    float* hbuf[2] = {h0, h1};
    const long XT_BS = (long)TT * CHW;
    const long H_BS  = (long)CHW;

    for (int t = 0; t < TT; ++t) {
        const float* xt = x + (size_t)t * CHW;
        float* hcur = hbuf[t & 1];
        float* hnext = (t == TT - 1) ? out : hbuf[(t + 1) & 1];

        // attention: att01[z=0] = conv(h,Wa)+ba+bua ; att01[z=1] = conv(xt,Ua)
        conv_mfma<1><<<dim3(60, 4, 2), dim3(256), 0, stream>>>(
            hcur, H_BS, nullptr, xt, XT_BS, wta_hi, wta_lo, ba, bua, att01, 256);
        add_tanh<<<dim3((n + 255) / 256), dim3(256), 0, stream>>>(
            att01, att01 + NCHW, att, n);

        att_e_row<<<dim3(BB * HH), dim3(256), 0, stream>>>(att, Va, e);
        softmax_kernel<<<dim3(BB), dim3(256), 0, stream>>>(e, a);

        // gates: g01[z=0] = conv(xt*a, Wx)+bx+bh ; g01[z=1] = conv(h, Uh)
        conv_mfma<2><<<dim3(60, 8, 2), dim3(256), 0, stream>>>(
            xt, XT_BS, a, hcur, H_BS, wtg_hi, wtg_lo, bx, bh, g01, 1024);

        gate_update<<<dim3((n + 255) / 256), dim3(256), 0, stream>>>(
            g01, g01 + 4 * NCHW, cb, hnext);
    }
}

// Round 4
// 803.617 us; speedup vs baseline: 9.9529x; 1.5127x over previous
//
#include <hip/hip_runtime.h>
#include <math.h>

#define BB 4
#define TT 4
#define CC 256
#define HH 30
#define WW 40
#define HWS (HH*WW)          // 1200
#define CHW (CC*HWS)         // 307200

typedef __attribute__((ext_vector_type(8))) _Float16 half8;
typedef __attribute__((ext_vector_type(4))) float f32x4;

// ---------------------------------------------------------------------------
// h0 = sum_t x[b,t,:,:,:]; c0 = h0
// ---------------------------------------------------------------------------
__global__ void init_hc(const float* __restrict__ x,
                        float* __restrict__ h, float* __restrict__ c) {
    int id = blockIdx.x * 256 + threadIdx.x;
    if (id >= BB * CHW) return;
    int b = id / CHW;
    int rem = id - b * CHW;
    float s = 0.f;
#pragma unroll
    for (int t = 0; t < TT; ++t)
        s += x[((size_t)b * TT + t) * CHW + rem];
    h[id] = s;
    c[id] = s;
}

// ---------------------------------------------------------------------------
// Pack weights to f16: layout [kg=k/8][Cout][k%8]
// k = (src? 2304:0) + tap*256 + ci  over K=4608
// ---------------------------------------------------------------------------
__global__ void pack_weights(const float* __restrict__ W1,
                             const float* __restrict__ W2,
                             _Float16* __restrict__ wt, int Cout) {
    int idx = blockIdx.x * 256 + threadIdx.x;
    if (idx >= 4608 * Cout) return;
    int k = idx / Cout;
    int n = idx - k * Cout;
    float v = (k < 2304) ? W1[(size_t)k * Cout + n]
                         : W2[(size_t)(k - 2304) * Cout + n];
    wt[((size_t)(k >> 3) * Cout + n) * 8 + (k & 7)] = (_Float16)v;
}

// ---------------------------------------------------------------------------
// MFMA dual 3x3 conv, f16, K-split over the two sources (blockIdx.z):
//   z=0: partial = conv(in0*scale, W1) + b1 + b2   (bias folded here)
//   z=1: partial = conv(in1, W2)
// out has two stacked [B,Cout,H,W] buffers (z selects).
// M-tile: 80 pixels (2 rows). LDS layout [cig(4)][pix(168)][8ci] f16.
// B (weights) read directly from packed global (256B/quad, L2-served).
// ---------------------------------------------------------------------------
template<int NW>
__global__ __launch_bounds__(256) void conv_mfma(
    const float* __restrict__ in0, long bs0, const float* __restrict__ scale,
    const float* __restrict__ in1, long bs1,
    const _Float16* __restrict__ wt,
    const float* __restrict__ b1, const float* __restrict__ b2,
    float* __restrict__ out, int Cout)
{
    __shared__ alignas(16) _Float16 s_a[4 * 168 * 8];

    const int tid = threadIdx.x;
    const int l = tid & 63, wv = tid >> 6;
    const int q = l >> 4, r = l & 15;
    const int mb = blockIdx.x;                 // 0..59
    const int b = mb / 15;
    const int pix0 = (mb % 15) * 80;
    const int y0 = (mb % 15) * 2;
    const int n0 = blockIdx.y * (4 * NW * 16) + wv * (NW * 16);
    const int z = blockIdx.z;

    const float* inp = z ? (in1 + (size_t)b * bs1) : (in0 + (size_t)b * bs0);
    const float* scl = z ? nullptr : scale;

    f32x4 acc[5][NW];
#pragma unroll
    for (int nt = 0; nt < NW; ++nt) {
        int co = n0 + nt * 16 + r;
        float bias = z ? 0.f : (b1[co] + b2[co]);
        f32x4 bv = {bias, bias, bias, bias};
#pragma unroll
        for (int mt = 0; mt < 5; ++mt) acc[mt][nt] = bv;
    }

    for (int ci0 = 0; ci0 < CC; ci0 += 32) {
        __syncthreads();
        // stage 32 ci x 168 halo pixels, 8 ci per item, b128 writes
        for (int i = tid; i < 672; i += 256) {
            int cig = i / 168;
            int pix = i - cig * 168;
            int row = pix / 42;
            int px = pix - row * 42;
            int xx = px - 1, yy = y0 + row - 1;
            half8 hv = {0, 0, 0, 0, 0, 0, 0, 0};
            if (xx >= 0 && xx < WW && yy >= 0 && yy < HH) {
                const float* p0 = inp + (size_t)(ci0 + cig * 8) * HWS + yy * WW + xx;
                float sc = scl ? scl[(size_t)b * HWS + yy * WW + xx] : 1.f;
#pragma unroll
                for (int j = 0; j < 8; ++j)
                    hv[j] = (_Float16)(p0[(size_t)j * HWS] * sc);
            }
            *(half8*)&s_a[(cig * 168 + pix) * 8] = hv;
        }
        __syncthreads();

        const int kgb = z * 288 + (ci0 >> 3);
#pragma unroll
        for (int tap = 0; tap < 9; ++tap) {
            const int dy = tap / 3, dx = tap - dy * 3;
            const int kg = kgb + tap * 32 + q;
            half8 bf[NW];
#pragma unroll
            for (int nt = 0; nt < NW; ++nt) {
                size_t off = (size_t)kg * Cout + (n0 + nt * 16 + r);
                bf[nt] = ((const half8*)wt)[off];
            }
#pragma unroll
            for (int mt = 0; mt < 5; ++mt) {
                int p = mt * 16 + r;
                int ry = p / 40, rx = p - ry * 40;
                int hpix = (ry + dy) * 42 + rx + dx;
                half8 af = *(const half8*)&s_a[(q * 168 + hpix) * 8];
#pragma unroll
                for (int nt = 0; nt < NW; ++nt)
                    acc[mt][nt] = __builtin_amdgcn_mfma_f32_16x16x32_f16(
                        af, bf[nt], acc[mt][nt], 0, 0, 0);
            }
        }
    }

    out += (size_t)z * BB * Cout * HWS;
#pragma unroll
    for (int mt = 0; mt < 5; ++mt) {
#pragma unroll
        for (int nt = 0; nt < NW; ++nt) {
            int co = n0 + nt * 16 + r;
            int p = pix0 + mt * 16 + q * 4;
            *(f32x4*)&out[((size_t)b * Cout + co) * HWS + p] = acc[mt][nt];
        }
    }
}

// ---------------------------------------------------------------------------
// att = tanh(a0 + a1)
// ---------------------------------------------------------------------------
__global__ void add_tanh(const float* __restrict__ a0, const float* __restrict__ a1,
                         float* __restrict__ o, int n) {
    int id = blockIdx.x * 256 + threadIdx.x;
    if (id < n) o[id] = tanhf(a0[id] + a1[id]);
}

// ---------------------------------------------------------------------------
// e[b,y,x] = sum_{ca,tap} att[b,ca,y+dy-1,x+dx-1] * Va[tap,ca]
// ---------------------------------------------------------------------------
__global__ void att_e_row(const float* __restrict__ att,
                          const float* __restrict__ Va,
                          float* __restrict__ e) {
    __shared__ float red[6][40];
    int blk = blockIdx.x;
    int b = blk / HH, y = blk - b * HH;
    int t = threadIdx.x;
    if (t < 240) {
        int x = t % 40, g = t / 40;
        float acc = 0.f;
        for (int ca = g; ca < CC; ca += 6) {
            const float* base = att + ((size_t)b * CC + ca) * HWS;
#pragma unroll
            for (int dy = 0; dy < 3; ++dy) {
                int yy = y + dy - 1;
                if (yy < 0 || yy >= HH) continue;
#pragma unroll
                for (int dx = 0; dx < 3; ++dx) {
                    int xx = x + dx - 1;
                    if (xx < 0 || xx >= WW) continue;
                    acc = fmaf(base[yy * WW + xx], Va[(dy * 3 + dx) * CC + ca], acc);
                }
            }
        }
        red[g][x] = acc;
    }
    __syncthreads();
    if (t < 40) {
        float s = red[0][t] + red[1][t] + red[2][t] + red[3][t] + red[4][t] + red[5][t];
        e[(size_t)(b * HH + y) * WW + t] = s;
    }
}

// ---------------------------------------------------------------------------
// softmax over HW per batch
// ---------------------------------------------------------------------------
__global__ void softmax_kernel(const float* __restrict__ e, float* __restrict__ a) {
    __shared__ float red[256];
    int b = blockIdx.x;
    int tid = threadIdx.x;
    const float* eb = e + (size_t)b * HWS;

    float m = -1e30f;
    for (int i = tid; i < HWS; i += 256) m = fmaxf(m, eb[i]);
    red[tid] = m;
    __syncthreads();
    for (int s = 128; s > 0; s >>= 1) {
        if (tid < s) red[tid] = fmaxf(red[tid], red[tid + s]);
        __syncthreads();
    }
    m = red[0];
    __syncthreads();

    float sum = 0.f;
    for (int i = tid; i < HWS; i += 256) sum += expf(eb[i] - m);
    red[tid] = sum;
    __syncthreads();
    for (int s = 128; s > 0; s >>= 1) {
        if (tid < s) red[tid] += red[tid + s];
        __syncthreads();
    }
    float inv = 1.f / red[0];
    for (int i = tid; i < HWS; i += 256)
        a[(size_t)b * HWS + i] = expf(eb[i] - m) * inv;
}

// ---------------------------------------------------------------------------
// LSTM gate update, fusing the K-split partial sum: g = g0 + g1
// ---------------------------------------------------------------------------
__global__ void gate_update(const float* __restrict__ g0, const float* __restrict__ g1,
                            float* __restrict__ c, float* __restrict__ h_out) {
    int id = blockIdx.x * 256 + threadIdx.x;
    if (id >= BB * CHW) return;
    int b = id / CHW;
    int rem = id - b * CHW;
    size_t gbase = (size_t)b * 4 * CHW + rem;
    float gi = g0[gbase] + g1[gbase];
    float gf = g0[gbase + CHW] + g1[gbase + CHW];
    float gc = g0[gbase + 2 * (size_t)CHW] + g1[gbase + 2 * (size_t)CHW];
    float go = g0[gbase + 3 * (size_t)CHW] + g1[gbase + 3 * (size_t)CHW];
    float i_ = 1.f / (1.f + expf(-gi));
    float f_ = 1.f / (1.f + expf(-gf));
    float o_ = 1.f / (1.f + expf(-go));
    float cn = f_ * c[id] + i_ * tanhf(gc);
    c[id] = cn;
    h_out[id] = o_ * tanhf(cn);
}

// ---------------------------------------------------------------------------
extern "C" void kernel_launch(void* const* d_in, const int* in_sizes, int n_in,
                              void* d_out, int out_size, void* d_ws, size_t ws_size,
                              hipStream_t stream) {
    const float* x   = (const float*)d_in[0];
    const float* Wa  = (const float*)d_in[1];
    const float* ba  = (const float*)d_in[2];
    const float* Ua  = (const float*)d_in[3];
    const float* bua = (const float*)d_in[4];
    const float* Va  = (const float*)d_in[5];
    const float* Wx  = (const float*)d_in[6];
    const float* bx  = (const float*)d_in[7];
    const float* Uh  = (const float*)d_in[8];
    const float* bh  = (const float*)d_in[9];
    float* out = (float*)d_out;

    char* wsb = (char*)d_ws;
    const size_t NCHW = (size_t)BB * CHW;
    _Float16* wtg = (_Float16*)wsb;               wsb += (size_t)4608 * 1024 * 2;
    _Float16* wta = (_Float16*)wsb;               wsb += (size_t)4608 * 256 * 2;
    float* h0   = (float*)wsb;                    wsb += NCHW * 4;
    float* h1   = (float*)wsb;                    wsb += NCHW * 4;
    float* cb   = (float*)wsb;                    wsb += NCHW * 4;
    float* att01= (float*)wsb;                    wsb += 2 * NCHW * 4;   // z-stacked
    float* att  = (float*)wsb;                    wsb += NCHW * 4;
    float* g01  = (float*)wsb;                    wsb += 8 * NCHW * 4;   // z-stacked
    float* e    = (float*)wsb;                    wsb += (size_t)BB * HWS * 4;
    float* a    = (float*)wsb;

    pack_weights<<<dim3((4608 * 1024 + 255) / 256), dim3(256), 0, stream>>>(
        Wx, Uh, wtg, 1024);
    pack_weights<<<dim3((4608 * 256 + 255) / 256), dim3(256), 0, stream>>>(
        Wa, Ua, wta, 256);

    const int n = (int)NCHW;
    init_hc<<<dim3((n + 255) / 256), dim3(256), 0, stream>>>(x, h0, cb);

    float* hbuf[2] = {h0, h1};
    const long XT_BS = (long)TT * CHW;
    const long H_BS  = (long)CHW;

    for (int t = 0; t < TT; ++t) {
        const float* xt = x + (size_t)t * CHW;
        float* hcur = hbuf[t & 1];
        float* hnext = (t == TT - 1) ? out : hbuf[(t + 1) & 1];

        // attention: att01[z=0] = conv(h,Wa)+ba+bua ; att01[z=1] = conv(xt,Ua)
        conv_mfma<1><<<dim3(60, 4, 2), dim3(256), 0, stream>>>(
            hcur, H_BS, nullptr, xt, XT_BS, wta, ba, bua, att01, 256);
        add_tanh<<<dim3((n + 255) / 256), dim3(256), 0, stream>>>(
            att01, att01 + NCHW, att, n);

        att_e_row<<<dim3(BB * HH), dim3(256), 0, stream>>>(att, Va, e);
        softmax_kernel<<<dim3(BB), dim3(256), 0, stream>>>(e, a);

        // gates: g01[z=0] = conv(xt*a, Wx)+bx+bh ; g01[z=1] = conv(h, Uh)
        conv_mfma<2><<<dim3(60, 8, 2), dim3(256), 0, stream>>>(
            xt, XT_BS, a, hcur, H_BS, wtg, bx, bh, g01, 1024);

        gate_update<<<dim3((n + 255) / 256), dim3(256), 0, stream>>>(
            g01, g01 + 4 * NCHW, cb, hnext);
    }
}

// Round 5
// 648.592 us; speedup vs baseline: 12.3319x; 1.2390x over previous
//
#include <hip/hip_runtime.h>
#include <math.h>

#define BB 4
#define TT 4
#define CC 256
#define HH 30
#define WW 40
#define HWS (HH*WW)          // 1200
#define CHW (CC*HWS)         // 307200

typedef __attribute__((ext_vector_type(8))) _Float16 half8;
typedef __attribute__((ext_vector_type(4))) float f32x4;

// ---------------------------------------------------------------------------
// h0 = sum_t x[b,t,:,:,:]; c0 = h0
// ---------------------------------------------------------------------------
__global__ void init_hc(const float* __restrict__ x,
                        float* __restrict__ h, float* __restrict__ c) {
    int id = blockIdx.x * 256 + threadIdx.x;
    if (id >= BB * CHW) return;
    int b = id / CHW;
    int rem = id - b * CHW;
    float s = 0.f;
#pragma unroll
    for (int t = 0; t < TT; ++t)
        s += x[((size_t)b * TT + t) * CHW + rem];
    h[id] = s;
    c[id] = s;
}

// ---------------------------------------------------------------------------
// Pack weights to f16: layout [kg=k/8][Cout][k%8]
// k = (src? 2304:0) + tap*256 + ci  over K=4608
// ---------------------------------------------------------------------------
__global__ void pack_weights(const float* __restrict__ W1,
                             const float* __restrict__ W2,
                             _Float16* __restrict__ wt, int Cout) {
    int idx = blockIdx.x * 256 + threadIdx.x;
    if (idx >= 4608 * Cout) return;
    int k = idx / Cout;
    int n = idx - k * Cout;
    float v = (k < 2304) ? W1[(size_t)k * Cout + n]
                         : W2[(size_t)(k - 2304) * Cout + n];
    wt[((size_t)(k >> 3) * Cout + n) * 8 + (k & 7)] = (_Float16)v;
}

// ---------------------------------------------------------------------------
// MFMA dual 3x3 conv, f16, K-split over the two sources (blockIdx.z):
//   z=0: partial = conv(in0*scale, W1) + b1 + b2   (bias folded here)
//   z=1: partial = conv(in1, W2)
// out has two stacked [B,Cout,H,W] buffers (z selects).
// M-tile: 80 pixels (2 rows). LDS layout [cig(4)][pix(168)][8ci] f16.
// B (weights) read directly from packed global (256B/quad, L2-served).
// ---------------------------------------------------------------------------
template<int NW>
__global__ __launch_bounds__(256) void conv_mfma(
    const float* __restrict__ in0, long bs0, const float* __restrict__ scale,
    const float* __restrict__ in1, long bs1,
    const _Float16* __restrict__ wt,
    const float* __restrict__ b1, const float* __restrict__ b2,
    float* __restrict__ out, int Cout)
{
    __shared__ alignas(16) _Float16 s_a[4 * 168 * 8];

    const int tid = threadIdx.x;
    const int l = tid & 63, wv = tid >> 6;
    const int q = l >> 4, r = l & 15;
    const int mb = blockIdx.x;                 // 0..59
    const int b = mb / 15;
    const int pix0 = (mb % 15) * 80;
    const int y0 = (mb % 15) * 2;
    const int n0 = blockIdx.y * (4 * NW * 16) + wv * (NW * 16);
    const int z = blockIdx.z;

    const float* inp = z ? (in1 + (size_t)b * bs1) : (in0 + (size_t)b * bs0);
    const float* scl = z ? nullptr : scale;

    f32x4 acc[5][NW];
#pragma unroll
    for (int nt = 0; nt < NW; ++nt) {
        int co = n0 + nt * 16 + r;
        float bias = z ? 0.f : (b1[co] + b2[co]);
        f32x4 bv = {bias, bias, bias, bias};
#pragma unroll
        for (int mt = 0; mt < 5; ++mt) acc[mt][nt] = bv;
    }

    for (int ci0 = 0; ci0 < CC; ci0 += 32) {
        __syncthreads();
        // stage 32 ci x 168 halo pixels, 8 ci per item, b128 writes
        for (int i = tid; i < 672; i += 256) {
            int cig = i / 168;
            int pix = i - cig * 168;
            int row = pix / 42;
            int px = pix - row * 42;
            int xx = px - 1, yy = y0 + row - 1;
            half8 hv = {0, 0, 0, 0, 0, 0, 0, 0};
            if (xx >= 0 && xx < WW && yy >= 0 && yy < HH) {
                const float* p0 = inp + (size_t)(ci0 + cig * 8) * HWS + yy * WW + xx;
                float sc = scl ? scl[(size_t)b * HWS + yy * WW + xx] : 1.f;
#pragma unroll
                for (int j = 0; j < 8; ++j)
                    hv[j] = (_Float16)(p0[(size_t)j * HWS] * sc);
            }
            *(half8*)&s_a[(cig * 168 + pix) * 8] = hv;
        }
        __syncthreads();

        const int kgb = z * 288 + (ci0 >> 3);
#pragma unroll
        for (int tap = 0; tap < 9; ++tap) {
            const int dy = tap / 3, dx = tap - dy * 3;
            const int kg = kgb + tap * 32 + q;
            half8 bf[NW];
#pragma unroll
            for (int nt = 0; nt < NW; ++nt) {
                size_t off = (size_t)kg * Cout + (n0 + nt * 16 + r);
                bf[nt] = ((const half8*)wt)[off];
            }
#pragma unroll
            for (int mt = 0; mt < 5; ++mt) {
                int p = mt * 16 + r;
                int ry = p / 40, rx = p - ry * 40;
                int hpix = (ry + dy) * 42 + rx + dx;
                half8 af = *(const half8*)&s_a[(q * 168 + hpix) * 8];
#pragma unroll
                for (int nt = 0; nt < NW; ++nt)
                    acc[mt][nt] = __builtin_amdgcn_mfma_f32_16x16x32_f16(
                        af, bf[nt], acc[mt][nt], 0, 0, 0);
            }
        }
    }

    out += (size_t)z * BB * Cout * HWS;
#pragma unroll
    for (int mt = 0; mt < 5; ++mt) {
#pragma unroll
        for (int nt = 0; nt < NW; ++nt) {
            int co = n0 + nt * 16 + r;
            int p = pix0 + mt * 16 + q * 4;
            *(f32x4*)&out[((size_t)b * Cout + co) * HWS + p] = acc[mt][nt];
        }
    }
}

// ---------------------------------------------------------------------------
// att = tanh(a0 + a1)
// ---------------------------------------------------------------------------
__global__ void add_tanh(const float* __restrict__ a0, const float* __restrict__ a1,
                         float* __restrict__ o, int n) {
    int id = blockIdx.x * 256 + threadIdx.x;
    if (id < n) o[id] = tanhf(a0[id] + a1[id]);
}

// ---------------------------------------------------------------------------
// K-split attention score: part[b][ch][p] = sum_{ca in chunk ch} sum_tap
//   att[b,ca,y+dy-1,x+dx-1] * Va[tap,ca]
// grid (19 pixel-tiles, B, 8 chunks), block 256 = 4 waves x 64 px.
// Each wave covers 64 consecutive pixels (coalesced), 8 ca each; LDS reduce.
// ---------------------------------------------------------------------------
__global__ __launch_bounds__(256) void att_e_part(
    const float* __restrict__ att, const float* __restrict__ Va,
    float* __restrict__ part)
{
    __shared__ float red[4][64];
    const int lane = threadIdx.x & 63, wv = threadIdx.x >> 6;
    const int p = blockIdx.x * 64 + lane;
    const int b = blockIdx.y, ch = blockIdx.z;
    const bool valid = (p < HWS);
    const int pc = valid ? p : 0;
    const int y = pc / WW, x = pc - (pc / WW) * WW;

    float acc = 0.f;
    if (valid) {
        const int ca0 = ch * 32 + wv * 8;
#pragma unroll
        for (int j = 0; j < 8; ++j) {
            const int ca = ca0 + j;
            const float* base = att + ((size_t)b * CC + ca) * HWS;
            const float* va = Va + ca;
#pragma unroll
            for (int dy = 0; dy < 3; ++dy) {
                int yy = y + dy - 1;
                if (yy < 0 || yy >= HH) continue;
#pragma unroll
                for (int dx = 0; dx < 3; ++dx) {
                    int xx = x + dx - 1;
                    if (xx < 0 || xx >= WW) continue;
                    acc = fmaf(base[yy * WW + xx], va[(dy * 3 + dx) * CC], acc);
                }
            }
        }
    }
    red[wv][lane] = acc;
    __syncthreads();
    if (wv == 0 && valid)
        part[((size_t)b * 8 + ch) * HWS + p] =
            red[0][lane] + red[1][lane] + red[2][lane] + red[3][lane];
}

// ---------------------------------------------------------------------------
// softmax over HW per batch, summing the 8 K-split partials first (in LDS)
// ---------------------------------------------------------------------------
__global__ __launch_bounds__(256) void softmax_kernel(
    const float* __restrict__ part, float* __restrict__ a)
{
    __shared__ float se[HWS];
    __shared__ float red[256];
    int b = blockIdx.x;
    int tid = threadIdx.x;

    for (int i = tid; i < HWS; i += 256) {
        float s = 0.f;
#pragma unroll
        for (int ch = 0; ch < 8; ++ch)
            s += part[((size_t)b * 8 + ch) * HWS + i];
        se[i] = s;
    }
    __syncthreads();

    float m = -1e30f;
    for (int i = tid; i < HWS; i += 256) m = fmaxf(m, se[i]);
    red[tid] = m;
    __syncthreads();
    for (int s = 128; s > 0; s >>= 1) {
        if (tid < s) red[tid] = fmaxf(red[tid], red[tid + s]);
        __syncthreads();
    }
    m = red[0];
    __syncthreads();

    float sum = 0.f;
    for (int i = tid; i < HWS; i += 256) {
        float v = expf(se[i] - m);
        se[i] = v;
        sum += v;
    }
    red[tid] = sum;
    __syncthreads();
    for (int s = 128; s > 0; s >>= 1) {
        if (tid < s) red[tid] += red[tid + s];
        __syncthreads();
    }
    float inv = 1.f / red[0];
    for (int i = tid; i < HWS; i += 256)
        a[(size_t)b * HWS + i] = se[i] * inv;
}

// ---------------------------------------------------------------------------
// LSTM gate update, fusing the K-split partial sum: g = g0 + g1
// ---------------------------------------------------------------------------
__global__ void gate_update(const float* __restrict__ g0, const float* __restrict__ g1,
                            float* __restrict__ c, float* __restrict__ h_out) {
    int id = blockIdx.x * 256 + threadIdx.x;
    if (id >= BB * CHW) return;
    int b = id / CHW;
    int rem = id - b * CHW;
    size_t gbase = (size_t)b * 4 * CHW + rem;
    float gi = g0[gbase] + g1[gbase];
    float gf = g0[gbase + CHW] + g1[gbase + CHW];
    float gc = g0[gbase + 2 * (size_t)CHW] + g1[gbase + 2 * (size_t)CHW];
    float go = g0[gbase + 3 * (size_t)CHW] + g1[gbase + 3 * (size_t)CHW];
    float i_ = 1.f / (1.f + expf(-gi));
    float f_ = 1.f / (1.f + expf(-gf));
    float o_ = 1.f / (1.f + expf(-go));
    float cn = f_ * c[id] + i_ * tanhf(gc);
    c[id] = cn;
    h_out[id] = o_ * tanhf(cn);
}

// ---------------------------------------------------------------------------
extern "C" void kernel_launch(void* const* d_in, const int* in_sizes, int n_in,
                              void* d_out, int out_size, void* d_ws, size_t ws_size,
                              hipStream_t stream) {
    const float* x   = (const float*)d_in[0];
    const float* Wa  = (const float*)d_in[1];
    const float* ba  = (const float*)d_in[2];
    const float* Ua  = (const float*)d_in[3];
    const float* bua = (const float*)d_in[4];
    const float* Va  = (const float*)d_in[5];
    const float* Wx  = (const float*)d_in[6];
    const float* bx  = (const float*)d_in[7];
    const float* Uh  = (const float*)d_in[8];
    const float* bh  = (const float*)d_in[9];
    float* out = (float*)d_out;

    char* wsb = (char*)d_ws;
    const size_t NCHW = (size_t)BB * CHW;
    _Float16* wtg = (_Float16*)wsb;               wsb += (size_t)4608 * 1024 * 2;
    _Float16* wta = (_Float16*)wsb;               wsb += (size_t)4608 * 256 * 2;
    float* h0   = (float*)wsb;                    wsb += NCHW * 4;
    float* h1   = (float*)wsb;                    wsb += NCHW * 4;
    float* cb   = (float*)wsb;                    wsb += NCHW * 4;
    float* att01= (float*)wsb;                    wsb += 2 * NCHW * 4;   // z-stacked
    float* att  = (float*)wsb;                    wsb += NCHW * 4;
    float* g01  = (float*)wsb;                    wsb += 8 * NCHW * 4;   // z-stacked
    float* part = (float*)wsb;                    wsb += (size_t)BB * 8 * HWS * 4;
    float* a    = (float*)wsb;

    pack_weights<<<dim3((4608 * 1024 + 255) / 256), dim3(256), 0, stream>>>(
        Wx, Uh, wtg, 1024);
    pack_weights<<<dim3((4608 * 256 + 255) / 256), dim3(256), 0, stream>>>(
        Wa, Ua, wta, 256);

    const int n = (int)NCHW;
    init_hc<<<dim3((n + 255) / 256), dim3(256), 0, stream>>>(x, h0, cb);

    float* hbuf[2] = {h0, h1};
    const long XT_BS = (long)TT * CHW;
    const long H_BS  = (long)CHW;

    for (int t = 0; t < TT; ++t) {
        const float* xt = x + (size_t)t * CHW;
        float* hcur = hbuf[t & 1];
        float* hnext = (t == TT - 1) ? out : hbuf[(t + 1) & 1];

        // attention: att01[z=0] = conv(h,Wa)+ba+bua ; att01[z=1] = conv(xt,Ua)
        conv_mfma<1><<<dim3(60, 4, 2), dim3(256), 0, stream>>>(
            hcur, H_BS, nullptr, xt, XT_BS, wta, ba, bua, att01, 256);
        add_tanh<<<dim3((n + 255) / 256), dim3(256), 0, stream>>>(
            att01, att01 + NCHW, att, n);

        // e-partials (K-split over ca) + softmax (sums partials)
        att_e_part<<<dim3(19, BB, 8), dim3(256), 0, stream>>>(att, Va, part);
        softmax_kernel<<<dim3(BB), dim3(256), 0, stream>>>(part, a);

        // gates: g01[z=0] = conv(xt*a, Wx)+bx+bh ; g01[z=1] = conv(h, Uh)
        conv_mfma<2><<<dim3(60, 8, 2), dim3(256), 0, stream>>>(
            xt, XT_BS, a, hcur, H_BS, wtg, bx, bh, g01, 1024);

        gate_update<<<dim3((n + 255) / 256), dim3(256), 0, stream>>>(
            g01, g01 + 4 * NCHW, cb, hnext);
    }
}